// Round 1
// baseline (986.378 us; speedup 1.0000x reference)
//
#include <hip/hip_runtime.h>
#include <math.h>
#include <stdint.h>

#define E_EDGES 131072
#define NN 32768      // NUM_NODES
#define DMEM 256
#define DEDGE 128
#define TDIM 64
#define HID 512
#define MSGD 256
#define INDIM 704     // 2*256+128+64

typedef __bf16 bf16_t;
typedef bf16_t bf16x8 __attribute__((ext_vector_type(8)));
typedef float f32x4 __attribute__((ext_vector_type(4)));

__device__ __forceinline__ unsigned short f2bf(float f) {
  unsigned int u = __float_as_uint(f);
  u += 0x7FFF + ((u >> 16) & 1);   // round-to-nearest-even
  return (unsigned short)(u >> 16);
}

__device__ __forceinline__ void gl_lds16(const bf16_t* g, bf16_t* l) {
  __builtin_amdgcn_global_load_lds(
      (__attribute__((address_space(1))) void*)(g),
      (__attribute__((address_space(3))) void*)(l), 16, 0, 0);
}

// ---------------- pack X = [src | dst | edge | cos(t*w+b)] -> bf16 ----------------
__global__ void pack_x(const float* __restrict__ src, const float* __restrict__ dmem,
                       const float* __restrict__ edge, const float* __restrict__ rel,
                       const float* __restrict__ tw, const float* __restrict__ tb,
                       unsigned short* __restrict__ Xb) {
  const int G = INDIM / 4; // 176 groups of 4
  int idx = blockIdx.x * 256 + threadIdx.x;
  if (idx >= E_EDGES * G) return;
  int row = idx / G;
  int g = idx - row * G;
  float4 v;
  if (g < 64)        v = ((const float4*)(src  + (size_t)row * 256))[g];
  else if (g < 128)  v = ((const float4*)(dmem + (size_t)row * 256))[g - 64];
  else if (g < 160)  v = ((const float4*)(edge + (size_t)row * 128))[g - 128];
  else {
    int k = (g - 160) * 4;
    float rt = rel[row];
    v.x = cosf(rt * tw[k + 0] + tb[k + 0]);
    v.y = cosf(rt * tw[k + 1] + tb[k + 1]);
    v.z = cosf(rt * tw[k + 2] + tb[k + 2]);
    v.w = cosf(rt * tw[k + 3] + tb[k + 3]);
  }
  ushort4 o;
  o.x = f2bf(v.x); o.y = f2bf(v.y); o.z = f2bf(v.z); o.w = f2bf(v.w);
  ((ushort4*)(Xb + (size_t)row * INDIM))[g] = o;
}

__global__ void cvt_bf16(const float* __restrict__ in, unsigned short* __restrict__ out, int n) {
  int i = blockIdx.x * 256 + threadIdx.x;
  if (i < n) out[i] = f2bf(in[i]);
}

// ---------------- m97-style bf16 MFMA GEMM: C[M,N] = A[M,K] @ B[N,K]^T + bias ----------------
// BM=BN=128, BK=32, 256 threads = 4 waves, each wave 64x64 via 4x4 of 16x16x32 MFMA.
template <int ACT, int OUTBF>
__global__ __launch_bounds__(256) void gemm_bt(const bf16_t* __restrict__ A,
                                               const bf16_t* __restrict__ B,
                                               const float* __restrict__ bias,
                                               void* __restrict__ Cout,
                                               int M, int N, int K) {
  __shared__ alignas(16) bf16_t sA[128 * 32];
  __shared__ alignas(16) bf16_t sB[128 * 32];
  const int t = threadIdx.x;
  const int lane = t & 63;
  const int wave = t >> 6;
  const int wm = (wave >> 1) * 64;
  const int wn = (wave & 1) * 64;
  const int bm = blockIdx.y, bn = blockIdx.x;

  f32x4 acc[4][4];
#pragma unroll
  for (int i = 0; i < 4; i++)
#pragma unroll
    for (int j = 0; j < 4; j++) acc[i][j] = (f32x4){0.f, 0.f, 0.f, 0.f};

  const int r64 = t >> 2;        // 0..63 (row within half-tile)
  const int c8 = (t & 3) * 8;    // 8-elem column group
  const bf16_t* gA = A + ((size_t)bm * 128 + r64) * K + c8;
  const bf16_t* gB = B + ((size_t)bn * 128 + r64) * K + c8;
  bf16_t* lA = sA + (size_t)t * 8;   // byte offset t*16 == wave base + lane*16
  bf16_t* lB = sB + (size_t)t * 8;
  const size_t gstep = (size_t)64 * K;

  const int lrow = lane & 15;
  const int kq = (lane >> 4) * 8;

  for (int k0 = 0; k0 < K; k0 += 32) {
    gl_lds16(gA, lA);
    gl_lds16(gA + gstep, lA + 2048);
    gl_lds16(gB, lB);
    gl_lds16(gB + gstep, lB + 2048);
    gA += 32; gB += 32;
    __syncthreads();
    bf16x8 af[4], bfr[4];
#pragma unroll
    for (int i = 0; i < 4; i++) af[i] = *(const bf16x8*)(sA + (wm + i * 16 + lrow) * 32 + kq);
#pragma unroll
    for (int i = 0; i < 4; i++) bfr[i] = *(const bf16x8*)(sB + (wn + i * 16 + lrow) * 32 + kq);
#pragma unroll
    for (int mi = 0; mi < 4; mi++)
#pragma unroll
      for (int ni = 0; ni < 4; ni++)
        acc[mi][ni] = __builtin_amdgcn_mfma_f32_16x16x32_bf16(af[mi], bfr[ni], acc[mi][ni], 0, 0, 0);
    __syncthreads();
  }

  const int crow = (lane >> 4) * 4;
  const int ccol = lane & 15;
#pragma unroll
  for (int ni = 0; ni < 4; ni++) {
    int gcol = bn * 128 + wn + ni * 16 + ccol;
    float bv = bias[gcol];
#pragma unroll
    for (int mi = 0; mi < 4; mi++) {
#pragma unroll
      for (int r = 0; r < 4; r++) {
        size_t grow = (size_t)bm * 128 + wm + mi * 16 + crow + r;
        float v = acc[mi][ni][r] + bv;
        if (ACT) v = fmaxf(v, 0.f);
        if (OUTBF) ((unsigned short*)Cout)[grow * N + gcol] = f2bf(v);
        else       ((float*)Cout)[grow * N + gcol] = v;
      }
    }
  }
}

// ---------------- unique / segment machinery ----------------
__global__ void mark_k(const int* __restrict__ dst, int* __restrict__ flags,
                       float* __restrict__ counts) {
  int e = blockIdx.x * 256 + threadIdx.x;
  if (e < E_EDGES) {
    int id = dst[e];
    flags[id] = 1;
    atomicAdd(&counts[id], 1.0f);
  }
}

__global__ void scatter_sum(const int* __restrict__ dst, const float* __restrict__ msg,
                            float* __restrict__ sums) {
  int e = blockIdx.x;
  int t = threadIdx.x;
  int id = dst[e];
  atomicAdd(&sums[(size_t)id * 256 + t], msg[(size_t)e * 256 + t]);
}

__global__ void fill_k(float* __restrict__ uo, int* __restrict__ slot_id) {
  int j = blockIdx.x * 256 + threadIdx.x;
  if (j < NN) { uo[j] = (float)NN; slot_id[j] = -1; }
}

__global__ void scan_k(const int* __restrict__ flags, int* __restrict__ rank) {
  __shared__ int part[1024];
  int t = threadIdx.x;
  int base = t * 32;
  int s = 0;
  for (int i = 0; i < 32; i++) s += flags[base + i];
  part[t] = s;
  __syncthreads();
  for (int off = 1; off < 1024; off <<= 1) {
    int v = (t >= off) ? part[t - off] : 0;
    __syncthreads();
    part[t] += v;
    __syncthreads();
  }
  int run = (t == 0) ? 0 : part[t - 1];
  for (int i = 0; i < 32; i++) { rank[base + i] = run; run += flags[base + i]; }
}

__global__ void scatter_ids(const int* __restrict__ flags, const int* __restrict__ rank,
                            float* __restrict__ uo, int* __restrict__ slot_id) {
  int id = blockIdx.x * 256 + threadIdx.x;
  if (id < NN && flags[id]) {
    int s = rank[id];
    uo[s] = (float)id;
    slot_id[s] = id;
  }
}

__global__ void agg_pack(const int* __restrict__ slot_id, const float* __restrict__ sums,
                         const float* __restrict__ counts, const float* __restrict__ dmem,
                         unsigned short* __restrict__ aggb, unsigned short* __restrict__ prevb) {
  int j = blockIdx.x, t = threadIdx.x;
  int id = slot_id[j];
  float a = 0.f;
  if (id >= 0) a = sums[(size_t)id * 256 + t] / fmaxf(counts[id], 1.f);
  aggb[(size_t)j * 256 + t] = f2bf(a);
  prevb[(size_t)j * 256 + t] = f2bf(dmem[(size_t)j * 256 + t]);
}

__global__ void gru_gate(const float* __restrict__ gi, const float* __restrict__ gh,
                         const float* __restrict__ dmem, float* __restrict__ out) {
  int j = blockIdx.x, t = threadIdx.x;
  size_t b = (size_t)j * 768;
  float gir = gi[b + t], giz = gi[b + 256 + t], gin = gi[b + 512 + t];
  float ghr = gh[b + t], ghz = gh[b + 256 + t], ghn = gh[b + 512 + t];
  float r = 1.f / (1.f + expf(-(gir + ghr)));
  float z = 1.f / (1.f + expf(-(giz + ghz)));
  float n = tanhf(gin + r * ghn);
  float prev = dmem[(size_t)j * 256 + t];
  out[(size_t)NN + (size_t)j * 256 + t] = (1.f - z) * n + z * prev;
}

extern "C" void kernel_launch(void* const* d_in, const int* in_sizes, int n_in,
                              void* d_out, int out_size, void* d_ws, size_t ws_size,
                              hipStream_t stream) {
  const float* rel  = (const float*)d_in[0];
  const float* src  = (const float*)d_in[1];
  const float* dmem = (const float*)d_in[2];
  const float* edge = (const float*)d_in[3];
  const int*   dst  = (const int*)d_in[4];
  const float* tw   = (const float*)d_in[5];
  const float* tb   = (const float*)d_in[6];
  const float* w1   = (const float*)d_in[7];
  const float* b1   = (const float*)d_in[8];
  const float* w2   = (const float*)d_in[9];
  const float* b2   = (const float*)d_in[10];
  const float* wih  = (const float*)d_in[11];
  const float* whh  = (const float*)d_in[12];
  const float* bih  = (const float*)d_in[13];
  const float* bhh  = (const float*)d_in[14];

  char* ws = (char*)d_ws;
  size_t o = 0;
  auto take = [&](size_t bytes) -> char* {
    char* p = ws + o;
    o += (bytes + 255) & ~(size_t)255;
    return p;
  };

  unsigned short* Xb    = (unsigned short*)take((size_t)E_EDGES * INDIM * 2); // reused as gi
  unsigned short* hb    = (unsigned short*)take((size_t)E_EDGES * HID * 2);   // reused as gh
  float* msg            = (float*)take((size_t)E_EDGES * MSGD * 4);
  float* sums           = (float*)take((size_t)NN * 256 * 4);
  float* counts         = (float*)take((size_t)NN * 4);
  int*   flags          = (int*)take((size_t)NN * 4);
  int*   rank           = (int*)take((size_t)NN * 4);
  int*   slot_id        = (int*)take((size_t)NN * 4);
  unsigned short* aggb  = (unsigned short*)take((size_t)NN * 256 * 2);
  unsigned short* prevb = (unsigned short*)take((size_t)NN * 256 * 2);
  unsigned short* w1b   = (unsigned short*)take((size_t)HID * INDIM * 2);
  unsigned short* w2b   = (unsigned short*)take((size_t)MSGD * HID * 2);
  unsigned short* wihb  = (unsigned short*)take((size_t)768 * 256 * 2);
  unsigned short* whhb  = (unsigned short*)take((size_t)768 * 256 * 2);

  float* gi = (float*)Xb;   // X dead after GEMM1
  float* gh = (float*)hb;   // h dead after GEMM2
  float* outf = (float*)d_out;

  hipMemsetAsync(sums, 0, (size_t)NN * 256 * 4, stream);
  hipMemsetAsync(counts, 0, (size_t)NN * 4, stream);
  hipMemsetAsync(flags, 0, (size_t)NN * 4, stream);

  int n1 = HID * INDIM;
  int n2 = MSGD * HID;
  int n3 = 768 * 256;
  cvt_bf16<<<(n1 + 255) / 256, 256, 0, stream>>>(w1, w1b, n1);
  cvt_bf16<<<(n2 + 255) / 256, 256, 0, stream>>>(w2, w2b, n2);
  cvt_bf16<<<(n3 + 255) / 256, 256, 0, stream>>>(wih, wihb, n3);
  cvt_bf16<<<(n3 + 255) / 256, 256, 0, stream>>>(whh, whhb, n3);

  {
    int total = E_EDGES * (INDIM / 4);
    pack_x<<<(total + 255) / 256, 256, 0, stream>>>(src, dmem, edge, rel, tw, tb, Xb);
  }

  // h = relu(X @ w1^T + b1)   [M=131072, N=512, K=704]
  gemm_bt<1, 1><<<dim3(HID / 128, E_EDGES / 128), 256, 0, stream>>>(
      (const bf16_t*)Xb, (const bf16_t*)w1b, b1, hb, E_EDGES, HID, INDIM);
  // msg = h @ w2^T + b2       [M=131072, N=256, K=512]
  gemm_bt<0, 0><<<dim3(MSGD / 128, E_EDGES / 128), 256, 0, stream>>>(
      (const bf16_t*)hb, (const bf16_t*)w2b, b2, msg, E_EDGES, MSGD, HID);

  mark_k<<<E_EDGES / 256, 256, 0, stream>>>(dst, flags, counts);
  scatter_sum<<<E_EDGES, 256, 0, stream>>>(dst, msg, sums);
  fill_k<<<NN / 256, 256, 0, stream>>>(outf, slot_id);
  scan_k<<<1, 1024, 0, stream>>>(flags, rank);
  scatter_ids<<<NN / 256, 256, 0, stream>>>(flags, rank, outf, slot_id);
  agg_pack<<<NN, 256, 0, stream>>>(slot_id, sums, counts, dmem, aggb, prevb);

  // gi = agg @ w_ih^T + b_ih   [M=32768, N=768, K=256]
  gemm_bt<0, 0><<<dim3(768 / 128, NN / 128), 256, 0, stream>>>(
      (const bf16_t*)aggb, (const bf16_t*)wihb, bih, gi, NN, 768, 256);
  // gh = prev @ w_hh^T + b_hh
  gemm_bt<0, 0><<<dim3(768 / 128, NN / 128), 256, 0, stream>>>(
      (const bf16_t*)prevb, (const bf16_t*)whhb, bhh, gh, NN, 768, 256);

  gru_gate<<<NN, 256, 0, stream>>>(gi, gh, dmem, outf);
}

// Round 2
// 878.119 us; speedup vs baseline: 1.1233x; 1.1233x over previous
//
#include <hip/hip_runtime.h>
#include <math.h>
#include <stdint.h>

#define E_EDGES 131072
#define NN 32768      // NUM_NODES
#define DMEM 256
#define DEDGE 128
#define TDIM 64
#define HID 512
#define MSGD 256
#define INDIM 704     // 2*256+128+64

typedef __bf16 bf16_t;
typedef bf16_t bf16x8 __attribute__((ext_vector_type(8)));
typedef float f32x4 __attribute__((ext_vector_type(4)));

__device__ __forceinline__ unsigned short f2bf(float f) {
  unsigned int u = __float_as_uint(f);
  u += 0x7FFF + ((u >> 16) & 1);   // round-to-nearest-even
  return (unsigned short)(u >> 16);
}

__device__ __forceinline__ void gl_lds16(const bf16_t* g, bf16_t* l) {
  __builtin_amdgcn_global_load_lds(
      (__attribute__((address_space(1))) void*)(g),
      (__attribute__((address_space(3))) void*)(l), 16, 0, 0);
}

// ---------------- pack X = [src | dst | edge | cos(t*w+b)] -> bf16 ----------------
__global__ void pack_x(const float* __restrict__ src, const float* __restrict__ dmem,
                       const float* __restrict__ edge, const float* __restrict__ rel,
                       const float* __restrict__ tw, const float* __restrict__ tb,
                       unsigned short* __restrict__ Xb) {
  const int G = INDIM / 4; // 176 groups of 4
  int idx = blockIdx.x * 256 + threadIdx.x;
  if (idx >= E_EDGES * G) return;
  int row = idx / G;
  int g = idx - row * G;
  float4 v;
  if (g < 64)        v = ((const float4*)(src  + (size_t)row * 256))[g];
  else if (g < 128)  v = ((const float4*)(dmem + (size_t)row * 256))[g - 64];
  else if (g < 160)  v = ((const float4*)(edge + (size_t)row * 128))[g - 128];
  else {
    int k = (g - 160) * 4;
    float rt = rel[row];
    v.x = cosf(rt * tw[k + 0] + tb[k + 0]);
    v.y = cosf(rt * tw[k + 1] + tb[k + 1]);
    v.z = cosf(rt * tw[k + 2] + tb[k + 2]);
    v.w = cosf(rt * tw[k + 3] + tb[k + 3]);
  }
  ushort4 o;
  o.x = f2bf(v.x); o.y = f2bf(v.y); o.z = f2bf(v.z); o.w = f2bf(v.w);
  ((ushort4*)(Xb + (size_t)row * INDIM))[g] = o;
}

__global__ void cvt_bf16(const float* __restrict__ in, unsigned short* __restrict__ out, int n) {
  int i = blockIdx.x * 256 + threadIdx.x;
  if (i < n) out[i] = f2bf(in[i]);
}

// ---------------- bf16 MFMA GEMM: C[M,N] = A[M,K] @ B[N,K]^T + bias ----------------
// BM=128, BN=256, BK=32. 512 threads = 8 waves tiled 2(m) x 4(n), each wave 64x64.
// OMODE: 0 = f32 store, 1 = bf16 store + relu-able, 2 = atomicAdd scatter into
//        sums[dst[row]*256 + col] (fused segment-sum; N must be 256, bn==0).
// SWZ: 1 = 1-D grid with XCD-affine swizzle so bn-siblings of one bm share an XCD.
// GRUSEL: 1 = blockIdx.z selects (A,bias,Cout) vs (A2,bias2,Cout2).
template <int ACT, int OMODE, int SWZ, int GRUSEL>
__global__ __launch_bounds__(512) void gemm_bt2(
    const bf16_t* __restrict__ A, const bf16_t* __restrict__ B,
    const float* __restrict__ bias, void* __restrict__ Cout,
    const bf16_t* __restrict__ A2, const float* __restrict__ bias2,
    void* __restrict__ Cout2,
    const int* __restrict__ dstid, float* __restrict__ sums,
    int M, int N, int K) {
  __shared__ alignas(16) bf16_t sA[128 * 32];
  __shared__ alignas(16) bf16_t sB[256 * 32];

  int bm, bn;
  if (SWZ) {
    int id = blockIdx.x;             // grid = (M/128)*(N/256), N/256 == 2
    bm = (id >> 4) * 8 + (id & 7);   // 16-block chunk = 8 bm x 2 bn on 8 XCDs
    bn = (id >> 3) & 1;
  } else {
    bm = blockIdx.y; bn = blockIdx.x;
  }
  if (GRUSEL && blockIdx.z == 1) { A = A2; bias = bias2; Cout = Cout2; }

  const int t = threadIdx.x;
  const int lane = t & 63;
  const int wave = t >> 6;
  const int wm = (wave >> 2) * 64;   // 0 or 64
  const int wn = (wave & 3) * 64;    // 0..192

  f32x4 acc[4][4];
#pragma unroll
  for (int i = 0; i < 4; i++)
#pragma unroll
    for (int j = 0; j < 4; j++) acc[i][j] = (f32x4){0.f, 0.f, 0.f, 0.f};

  const int rA = t >> 2;          // 0..127
  const int cA = (t & 3) * 8;
  const bf16_t* gA = A + ((size_t)bm * 128 + rA) * K + cA;
  const bf16_t* gB = B + ((size_t)bn * 256 + rA) * K + cA;
  const size_t gB2off = (size_t)128 * K;
  bf16_t* lA = sA + (size_t)t * 8;
  bf16_t* lB = sB + (size_t)t * 8;

  const int lrow = lane & 15;
  const int kq = (lane >> 4) * 8;

  for (int k0 = 0; k0 < K; k0 += 32) {
    gl_lds16(gA, lA);
    gl_lds16(gB, lB);
    gl_lds16(gB + gB2off, lB + 4096);
    gA += 32; gB += 32;
    __syncthreads();
    bf16x8 af[4], bfr[4];
#pragma unroll
    for (int i = 0; i < 4; i++) af[i] = *(const bf16x8*)(sA + (wm + i * 16 + lrow) * 32 + kq);
#pragma unroll
    for (int i = 0; i < 4; i++) bfr[i] = *(const bf16x8*)(sB + (wn + i * 16 + lrow) * 32 + kq);
#pragma unroll
    for (int mi = 0; mi < 4; mi++)
#pragma unroll
      for (int ni = 0; ni < 4; ni++)
        acc[mi][ni] = __builtin_amdgcn_mfma_f32_16x16x32_bf16(af[mi], bfr[ni], acc[mi][ni], 0, 0, 0);
    __syncthreads();
  }

  const int crow = (lane >> 4) * 4;
  const int ccol = lane & 15;
  if (OMODE == 2) {
    // fused segment-sum: atomicAdd msg rows into sums[dst[row]]
#pragma unroll
    for (int mi = 0; mi < 4; mi++) {
      int id4[4];
#pragma unroll
      for (int r = 0; r < 4; r++)
        id4[r] = dstid[(size_t)bm * 128 + wm + mi * 16 + crow + r];
#pragma unroll
      for (int ni = 0; ni < 4; ni++) {
        int gcol = wn + ni * 16 + ccol;
        float bv = bias[gcol];
#pragma unroll
        for (int r = 0; r < 4; r++)
          atomicAdd(&sums[(size_t)id4[r] * 256 + gcol], acc[mi][ni][r] + bv);
      }
    }
  } else {
#pragma unroll
    for (int ni = 0; ni < 4; ni++) {
      int gcol = bn * 256 + wn + ni * 16 + ccol;
      float bv = bias[gcol];
#pragma unroll
      for (int mi = 0; mi < 4; mi++) {
#pragma unroll
        for (int r = 0; r < 4; r++) {
          size_t grow = (size_t)bm * 128 + wm + mi * 16 + crow + r;
          float v = acc[mi][ni][r] + bv;
          if (ACT) v = fmaxf(v, 0.f);
          if (OMODE == 1) ((unsigned short*)Cout)[grow * N + gcol] = f2bf(v);
          else            ((float*)Cout)[grow * N + gcol] = v;
        }
      }
    }
  }
}

// ---------------- unique / segment machinery ----------------
__global__ void mark_k(const int* __restrict__ dst, int* __restrict__ flags,
                       float* __restrict__ counts) {
  int e = blockIdx.x * 256 + threadIdx.x;
  if (e < E_EDGES) {
    int id = dst[e];
    flags[id] = 1;
    atomicAdd(&counts[id], 1.0f);
  }
}

__global__ void fill_k(float* __restrict__ uo, int* __restrict__ slot_id) {
  int j = blockIdx.x * 256 + threadIdx.x;
  if (j < NN) { uo[j] = (float)NN; slot_id[j] = -1; }
}

__global__ void scan_k(const int* __restrict__ flags, int* __restrict__ rank) {
  __shared__ int part[1024];
  int t = threadIdx.x;
  int base = t * 32;
  int s = 0;
  for (int i = 0; i < 32; i++) s += flags[base + i];
  part[t] = s;
  __syncthreads();
  for (int off = 1; off < 1024; off <<= 1) {
    int v = (t >= off) ? part[t - off] : 0;
    __syncthreads();
    part[t] += v;
    __syncthreads();
  }
  int run = (t == 0) ? 0 : part[t - 1];
  for (int i = 0; i < 32; i++) { rank[base + i] = run; run += flags[base + i]; }
}

__global__ void scatter_ids(const int* __restrict__ flags, const int* __restrict__ rank,
                            float* __restrict__ uo, int* __restrict__ slot_id) {
  int id = blockIdx.x * 256 + threadIdx.x;
  if (id < NN && flags[id]) {
    int s = rank[id];
    uo[s] = (float)id;
    slot_id[s] = id;
  }
}

__global__ void agg_pack(const int* __restrict__ slot_id, const float* __restrict__ sums,
                         const float* __restrict__ counts, const float* __restrict__ dmem,
                         unsigned short* __restrict__ aggb, unsigned short* __restrict__ prevb) {
  int j = blockIdx.x, t = threadIdx.x;
  int id = slot_id[j];
  float a = 0.f;
  if (id >= 0) a = sums[(size_t)id * 256 + t] / fmaxf(counts[id], 1.f);
  aggb[(size_t)j * 256 + t] = f2bf(a);
  prevb[(size_t)j * 256 + t] = f2bf(dmem[(size_t)j * 256 + t]);
}

__global__ void gru_gate(const float* __restrict__ gi, const float* __restrict__ gh,
                         const float* __restrict__ dmem, float* __restrict__ out) {
  int j = blockIdx.x, t = threadIdx.x;
  size_t b = (size_t)j * 768;
  float gir = gi[b + t], giz = gi[b + 256 + t], gin = gi[b + 512 + t];
  float ghr = gh[b + t], ghz = gh[b + 256 + t], ghn = gh[b + 512 + t];
  float r = 1.f / (1.f + expf(-(gir + ghr)));
  float z = 1.f / (1.f + expf(-(giz + ghz)));
  float n = tanhf(gin + r * ghn);
  float prev = dmem[(size_t)j * 256 + t];
  out[(size_t)NN + (size_t)j * 256 + t] = (1.f - z) * n + z * prev;
}

extern "C" void kernel_launch(void* const* d_in, const int* in_sizes, int n_in,
                              void* d_out, int out_size, void* d_ws, size_t ws_size,
                              hipStream_t stream) {
  const float* rel  = (const float*)d_in[0];
  const float* src  = (const float*)d_in[1];
  const float* dmem = (const float*)d_in[2];
  const float* edge = (const float*)d_in[3];
  const int*   dst  = (const int*)d_in[4];
  const float* tw   = (const float*)d_in[5];
  const float* tb   = (const float*)d_in[6];
  const float* w1   = (const float*)d_in[7];
  const float* b1   = (const float*)d_in[8];
  const float* w2   = (const float*)d_in[9];
  const float* b2   = (const float*)d_in[10];
  const float* wih  = (const float*)d_in[11];
  const float* whh  = (const float*)d_in[12];
  const float* bih  = (const float*)d_in[13];
  const float* bhh  = (const float*)d_in[14];

  char* ws = (char*)d_ws;
  size_t o = 0;
  auto take = [&](size_t bytes) -> char* {
    char* p = ws + o;
    o += (bytes + 255) & ~(size_t)255;
    return p;
  };

  unsigned short* Xb    = (unsigned short*)take((size_t)E_EDGES * INDIM * 2); // reused as gi
  unsigned short* hb    = (unsigned short*)take((size_t)E_EDGES * HID * 2);   // reused as gh
  float* sums           = (float*)take((size_t)NN * 256 * 4);
  float* counts         = (float*)take((size_t)NN * 4);
  int*   flags          = (int*)take((size_t)NN * 4);
  int*   rank           = (int*)take((size_t)NN * 4);
  int*   slot_id        = (int*)take((size_t)NN * 4);
  unsigned short* aggb  = (unsigned short*)take((size_t)NN * 256 * 2);
  unsigned short* prevb = (unsigned short*)take((size_t)NN * 256 * 2);
  unsigned short* w1b   = (unsigned short*)take((size_t)HID * INDIM * 2);
  unsigned short* w2b   = (unsigned short*)take((size_t)MSGD * HID * 2);
  unsigned short* wihb  = (unsigned short*)take((size_t)768 * 256 * 2);
  unsigned short* whhb  = (unsigned short*)take((size_t)768 * 256 * 2);

  float* gi = (float*)Xb;   // X dead after GEMM1 (100 MB < 184 MB)
  float* gh = (float*)hb;   // h dead after GEMM2 (100 MB < 134 MB)
  float* outf = (float*)d_out;

  hipMemsetAsync(sums, 0, (size_t)NN * 256 * 4, stream);
  hipMemsetAsync(counts, 0, (size_t)NN * 4, stream);
  hipMemsetAsync(flags, 0, (size_t)NN * 4, stream);

  int n1 = HID * INDIM;
  int n2 = MSGD * HID;
  int n3 = 768 * 256;
  cvt_bf16<<<(n1 + 255) / 256, 256, 0, stream>>>(w1, w1b, n1);
  cvt_bf16<<<(n2 + 255) / 256, 256, 0, stream>>>(w2, w2b, n2);
  cvt_bf16<<<(n3 + 255) / 256, 256, 0, stream>>>(wih, wihb, n3);
  cvt_bf16<<<(n3 + 255) / 256, 256, 0, stream>>>(whh, whhb, n3);

  {
    int total = E_EDGES * (INDIM / 4);
    pack_x<<<(total + 255) / 256, 256, 0, stream>>>(src, dmem, edge, rel, tw, tb, Xb);
  }

  mark_k<<<E_EDGES / 256, 256, 0, stream>>>(dst, flags, counts);

  // h = relu(X @ w1^T + b1)   [M=131072, N=512, K=704], bf16 out, XCD swizzle
  gemm_bt2<1, 1, 1, 0><<<dim3((E_EDGES / 128) * (HID / 256)), 512, 0, stream>>>(
      (const bf16_t*)Xb, (const bf16_t*)w1b, b1, hb,
      nullptr, nullptr, nullptr, nullptr, nullptr, E_EDGES, HID, INDIM);

  // msg = h @ w2^T + b2, scattered directly: sums[dst[e]] += msg[e]
  gemm_bt2<0, 2, 0, 0><<<dim3(1, E_EDGES / 128), 512, 0, stream>>>(
      (const bf16_t*)hb, (const bf16_t*)w2b, b2, nullptr,
      nullptr, nullptr, nullptr, dst, sums, E_EDGES, MSGD, HID);

  fill_k<<<NN / 256, 256, 0, stream>>>(outf, slot_id);
  scan_k<<<1, 1024, 0, stream>>>(flags, rank);
  scatter_ids<<<NN / 256, 256, 0, stream>>>(flags, rank, outf, slot_id);
  agg_pack<<<NN, 256, 0, stream>>>(slot_id, sums, counts, dmem, aggb, prevb);

  // gi = agg @ w_ih^T + b_ih ; gh = prev @ w_hh^T + b_hh  [M=32768, N=768, K=256]
  // one launch, z selects the pair
  gemm_bt2<0, 0, 0, 1><<<dim3(768 / 256, NN / 128, 2), 512, 0, stream>>>(
      (const bf16_t*)aggb, (const bf16_t*)wihb, bih, gi,
      (const bf16_t*)prevb, bhh, gh, nullptr, nullptr, NN, 768, 256);

  gru_gate<<<NN, 256, 0, stream>>>(gi, gh, dmem, outf);
}

// Round 3
// 831.549 us; speedup vs baseline: 1.1862x; 1.0560x over previous
//
#include <hip/hip_runtime.h>
#include <math.h>
#include <stdint.h>

#define E_EDGES 131072
#define NN 32768      // NUM_NODES
#define DMEM 256
#define DEDGE 128
#define TDIM 64
#define HID 512
#define MSGD 256
#define INDIM 704     // 2*256+128+64

typedef __bf16 bf16_t;
typedef bf16_t bf16x8 __attribute__((ext_vector_type(8)));
typedef float f32x4 __attribute__((ext_vector_type(4)));

__device__ __forceinline__ unsigned short f2bf(float f) {
  unsigned int u = __float_as_uint(f);
  u += 0x7FFF + ((u >> 16) & 1);   // round-to-nearest-even
  return (unsigned short)(u >> 16);
}

__device__ __forceinline__ void gl_lds16(const bf16_t* g, bf16_t* l) {
  __builtin_amdgcn_global_load_lds(
      (__attribute__((address_space(1))) void*)(g),
      (__attribute__((address_space(3))) void*)(l), 16, 0, 0);
}

__global__ void cvt_bf16(const float* __restrict__ in, unsigned short* __restrict__ out, int n) {
  int i = blockIdx.x * 256 + threadIdx.x;
  if (i < n) out[i] = f2bf(in[i]);
}

// ---------------- GEMM1 with fused input packing ----------------
// h = relu([src|dst|edge|cos(rel*tw+tb)] @ w1^T + b1), M=131072, N=512, K=704.
// BM=128, BN=256, BK=32. A-tile staged by loading f32 segments (or computing
// cos) and converting to bf16 via ds_write_b128; B staged via global_load_lds.
__global__ __launch_bounds__(512) void gemm1_fused(
    const float* __restrict__ src, const float* __restrict__ dmem,
    const float* __restrict__ edge, const float* __restrict__ rel,
    const float* __restrict__ tw, const float* __restrict__ tb,
    const bf16_t* __restrict__ w1b, const float* __restrict__ b1,
    unsigned short* __restrict__ hb) {
  __shared__ alignas(16) bf16_t sA[128 * 32];
  __shared__ alignas(16) bf16_t sB[256 * 32];
  __shared__ float sTW[64], sTB[64], sRel[128];

  int id = blockIdx.x;               // 2048 blocks: 8 bm x 2 bn per 16-chunk -> XCD-affine
  const int bm = (id >> 4) * 8 + (id & 7);
  const int bn = (id >> 3) & 1;

  const int t = threadIdx.x;
  const int lane = t & 63;
  const int wave = t >> 6;
  const int wm = (wave >> 2) * 64;
  const int wn = (wave & 3) * 64;

  if (t < 64) { sTW[t] = tw[t]; sTB[t] = tb[t]; }
  if (t >= 128 && t < 256) sRel[t - 128] = rel[(size_t)bm * 128 + (t - 128)];

  f32x4 acc[4][4];
#pragma unroll
  for (int i = 0; i < 4; i++)
#pragma unroll
    for (int j = 0; j < 4; j++) acc[i][j] = (f32x4){0.f, 0.f, 0.f, 0.f};

  // A staging: thread -> (row ar, col-group ac of 8)
  const int ar = t >> 2;           // 0..127
  const int ac = (t & 3) * 8;      // 0,8,16,24
  const size_t arow = (size_t)bm * 128 + ar;
  // B staging: global_load_lds, 2 rows-halves
  const bf16_t* gB = w1b + ((size_t)bn * 256 + (t >> 2)) * 704 + (t & 3) * 8;
  bf16_t* lB = sB + (size_t)t * 8;

  const int lrow = lane & 15;
  const int kq = (lane >> 4) * 8;

  for (int k0 = 0; k0 < INDIM; k0 += 32) {
    gl_lds16(gB, lB);
    gl_lds16(gB + (size_t)128 * 704, lB + 128 * 32);
    gB += 32;

    bf16x8 av;
    if (k0 < 640) {
      const float* p;
      if (k0 < 256)      p = src  + arow * 256 + k0 + ac;
      else if (k0 < 512) p = dmem + arow * 256 + (k0 - 256) + ac;
      else               p = edge + arow * 128 + (k0 - 512) + ac;
      f32x4 u = *(const f32x4*)p;
      f32x4 v = *(const f32x4*)(p + 4);
      av[0] = (bf16_t)u[0]; av[1] = (bf16_t)u[1]; av[2] = (bf16_t)u[2]; av[3] = (bf16_t)u[3];
      av[4] = (bf16_t)v[0]; av[5] = (bf16_t)v[1]; av[6] = (bf16_t)v[2]; av[7] = (bf16_t)v[3];
    } else {
      float rv = sRel[ar];
      int kk = (k0 - 640) + ac;
#pragma unroll
      for (int j = 0; j < 8; j++)
        av[j] = (bf16_t)cosf(rv * sTW[kk + j] + sTB[kk + j]);
    }
    *(bf16x8*)(sA + ar * 32 + ac) = av;

    __syncthreads();
    bf16x8 af[4], bfr[4];
#pragma unroll
    for (int i = 0; i < 4; i++) af[i] = *(const bf16x8*)(sA + (wm + i * 16 + lrow) * 32 + kq);
#pragma unroll
    for (int i = 0; i < 4; i++) bfr[i] = *(const bf16x8*)(sB + (wn + i * 16 + lrow) * 32 + kq);
#pragma unroll
    for (int mi = 0; mi < 4; mi++)
#pragma unroll
      for (int ni = 0; ni < 4; ni++)
        acc[mi][ni] = __builtin_amdgcn_mfma_f32_16x16x32_bf16(af[mi], bfr[ni], acc[mi][ni], 0, 0, 0);
    __syncthreads();
  }

  const int crow = (lane >> 4) * 4;
  const int ccol = lane & 15;
#pragma unroll
  for (int ni = 0; ni < 4; ni++) {
    int gcol = bn * 256 + wn + ni * 16 + ccol;
    float bv = b1[gcol];
#pragma unroll
    for (int mi = 0; mi < 4; mi++) {
#pragma unroll
      for (int r = 0; r < 4; r++) {
        size_t grow = (size_t)bm * 128 + wm + mi * 16 + crow + r;
        hb[grow * HID + gcol] = f2bf(fmaxf(acc[mi][ni][r] + bv, 0.f));
      }
    }
  }
}

// ---------------- generic bf16 MFMA GEMM: C[M,N] = A[M,K] @ B[N,K]^T + bias ----------------
// BM=128, BN=256, BK=32, 512 threads = 8 waves (2m x 4n), wave tile 64x64.
// OMODE: 1 = bf16 store (+relu if ACT), 2 = atomicAdd scatter sums[dst[row]*256+col].
// GRUSEL: blockIdx.z==1 -> (A2,bias2,Cout2).
template <int ACT, int OMODE, int GRUSEL>
__global__ __launch_bounds__(512) void gemm_bt2(
    const bf16_t* __restrict__ A, const bf16_t* __restrict__ B,
    const float* __restrict__ bias, void* __restrict__ Cout,
    const bf16_t* __restrict__ A2, const float* __restrict__ bias2,
    void* __restrict__ Cout2,
    const int* __restrict__ dstid, float* __restrict__ sums,
    int M, int N, int K) {
  __shared__ alignas(16) bf16_t sA[128 * 32];
  __shared__ alignas(16) bf16_t sB[256 * 32];

  int bm = blockIdx.y, bn = blockIdx.x;
  if (GRUSEL && blockIdx.z == 1) { A = A2; bias = bias2; Cout = Cout2; }

  const int t = threadIdx.x;
  const int lane = t & 63;
  const int wave = t >> 6;
  const int wm = (wave >> 2) * 64;
  const int wn = (wave & 3) * 64;

  f32x4 acc[4][4];
#pragma unroll
  for (int i = 0; i < 4; i++)
#pragma unroll
    for (int j = 0; j < 4; j++) acc[i][j] = (f32x4){0.f, 0.f, 0.f, 0.f};

  const int rA = t >> 2;
  const int cA = (t & 3) * 8;
  const bf16_t* gA = A + ((size_t)bm * 128 + rA) * K + cA;
  const bf16_t* gB = B + ((size_t)bn * 256 + rA) * K + cA;
  const size_t gB2off = (size_t)128 * K;
  bf16_t* lA = sA + (size_t)t * 8;
  bf16_t* lB = sB + (size_t)t * 8;

  const int lrow = lane & 15;
  const int kq = (lane >> 4) * 8;

  for (int k0 = 0; k0 < K; k0 += 32) {
    gl_lds16(gA, lA);
    gl_lds16(gB, lB);
    gl_lds16(gB + gB2off, lB + 4096);
    gA += 32; gB += 32;
    __syncthreads();
    bf16x8 af[4], bfr[4];
#pragma unroll
    for (int i = 0; i < 4; i++) af[i] = *(const bf16x8*)(sA + (wm + i * 16 + lrow) * 32 + kq);
#pragma unroll
    for (int i = 0; i < 4; i++) bfr[i] = *(const bf16x8*)(sB + (wn + i * 16 + lrow) * 32 + kq);
#pragma unroll
    for (int mi = 0; mi < 4; mi++)
#pragma unroll
      for (int ni = 0; ni < 4; ni++)
        acc[mi][ni] = __builtin_amdgcn_mfma_f32_16x16x32_bf16(af[mi], bfr[ni], acc[mi][ni], 0, 0, 0);
    __syncthreads();
  }

  const int crow = (lane >> 4) * 4;
  const int ccol = lane & 15;
  if (OMODE == 2) {
#pragma unroll
    for (int mi = 0; mi < 4; mi++) {
      int id4[4];
#pragma unroll
      for (int r = 0; r < 4; r++)
        id4[r] = dstid[(size_t)bm * 128 + wm + mi * 16 + crow + r];
#pragma unroll
      for (int ni = 0; ni < 4; ni++) {
        int gcol = wn + ni * 16 + ccol;
        float bv = bias[gcol];
#pragma unroll
        for (int r = 0; r < 4; r++)
          atomicAdd(&sums[(size_t)id4[r] * 256 + gcol], acc[mi][ni][r] + bv);
      }
    }
  } else {
#pragma unroll
    for (int ni = 0; ni < 4; ni++) {
      int gcol = bn * 256 + wn + ni * 16 + ccol;
      float bv = bias[gcol];
#pragma unroll
      for (int mi = 0; mi < 4; mi++) {
#pragma unroll
        for (int r = 0; r < 4; r++) {
          size_t grow = (size_t)bm * 128 + wm + mi * 16 + crow + r;
          float v = acc[mi][ni][r] + bv;
          if (ACT) v = fmaxf(v, 0.f);
          ((unsigned short*)Cout)[grow * N + gcol] = f2bf(v);
        }
      }
    }
  }
}

// ---------------- unique / segment machinery ----------------
__global__ void mark_k(const int* __restrict__ dst, int* __restrict__ flags,
                       float* __restrict__ counts) {
  int e = blockIdx.x * 256 + threadIdx.x;
  if (e < E_EDGES) {
    int id = dst[e];
    flags[id] = 1;
    atomicAdd(&counts[id], 1.0f);
  }
}

__global__ void fill_k(float* __restrict__ uo, int* __restrict__ slot_id) {
  int j = blockIdx.x * 256 + threadIdx.x;
  if (j < NN) { uo[j] = (float)NN; slot_id[j] = -1; }
}

__global__ void scan_k(const int* __restrict__ flags, int* __restrict__ rank) {
  __shared__ int part[1024];
  int t = threadIdx.x;
  int base = t * 32;
  int s = 0;
  for (int i = 0; i < 32; i++) s += flags[base + i];
  part[t] = s;
  __syncthreads();
  for (int off = 1; off < 1024; off <<= 1) {
    int v = (t >= off) ? part[t - off] : 0;
    __syncthreads();
    part[t] += v;
    __syncthreads();
  }
  int run = (t == 0) ? 0 : part[t - 1];
  for (int i = 0; i < 32; i++) { rank[base + i] = run; run += flags[base + i]; }
}

__global__ void scatter_ids(const int* __restrict__ flags, const int* __restrict__ rank,
                            float* __restrict__ uo, int* __restrict__ slot_id) {
  int id = blockIdx.x * 256 + threadIdx.x;
  if (id < NN && flags[id]) {
    int s = rank[id];
    uo[s] = (float)id;
    slot_id[s] = id;
  }
}

__global__ void agg_pack(const int* __restrict__ slot_id, const float* __restrict__ sums,
                         const float* __restrict__ counts, const float* __restrict__ dmem,
                         unsigned short* __restrict__ aggb, unsigned short* __restrict__ prevb) {
  int j = blockIdx.x, t = threadIdx.x;
  int id = slot_id[j];
  float a = 0.f;
  if (id >= 0) a = sums[(size_t)id * 256 + t] / fmaxf(counts[id], 1.f);
  aggb[(size_t)j * 256 + t] = f2bf(a);
  prevb[(size_t)j * 256 + t] = f2bf(dmem[(size_t)j * 256 + t]);
}

__global__ void gru_gate(const unsigned short* __restrict__ gi,
                         const unsigned short* __restrict__ gh,
                         const float* __restrict__ dmem, float* __restrict__ out) {
  int j = blockIdx.x, t = threadIdx.x;
  size_t b = (size_t)j * 768;
  auto bf = [](unsigned short u) { return __uint_as_float((unsigned int)u << 16); };
  float gir = bf(gi[b + t]), giz = bf(gi[b + 256 + t]), gin = bf(gi[b + 512 + t]);
  float ghr = bf(gh[b + t]), ghz = bf(gh[b + 256 + t]), ghn = bf(gh[b + 512 + t]);
  float r = 1.f / (1.f + expf(-(gir + ghr)));
  float z = 1.f / (1.f + expf(-(giz + ghz)));
  float n = tanhf(gin + r * ghn);
  float prev = dmem[(size_t)j * 256 + t];
  out[(size_t)NN + (size_t)j * 256 + t] = (1.f - z) * n + z * prev;
}

extern "C" void kernel_launch(void* const* d_in, const int* in_sizes, int n_in,
                              void* d_out, int out_size, void* d_ws, size_t ws_size,
                              hipStream_t stream) {
  const float* rel  = (const float*)d_in[0];
  const float* src  = (const float*)d_in[1];
  const float* dmem = (const float*)d_in[2];
  const float* edge = (const float*)d_in[3];
  const int*   dst  = (const int*)d_in[4];
  const float* tw   = (const float*)d_in[5];
  const float* tb   = (const float*)d_in[6];
  const float* w1   = (const float*)d_in[7];
  const float* b1   = (const float*)d_in[8];
  const float* w2   = (const float*)d_in[9];
  const float* b2   = (const float*)d_in[10];
  const float* wih  = (const float*)d_in[11];
  const float* whh  = (const float*)d_in[12];
  const float* bih  = (const float*)d_in[13];
  const float* bhh  = (const float*)d_in[14];

  char* ws = (char*)d_ws;
  size_t o = 0;
  auto take = [&](size_t bytes) -> char* {
    char* p = ws + o;
    o += (bytes + 255) & ~(size_t)255;
    return p;
  };

  unsigned short* hb    = (unsigned short*)take((size_t)E_EDGES * HID * 2);
  unsigned short* gib   = (unsigned short*)take((size_t)NN * 768 * 2);
  unsigned short* ghb   = (unsigned short*)take((size_t)NN * 768 * 2);
  float* sums           = (float*)take((size_t)NN * 256 * 4);
  float* counts         = (float*)take((size_t)NN * 4);
  int*   flags          = (int*)take((size_t)NN * 4);
  int*   rank           = (int*)take((size_t)NN * 4);
  int*   slot_id        = (int*)take((size_t)NN * 4);
  unsigned short* aggb  = (unsigned short*)take((size_t)NN * 256 * 2);
  unsigned short* prevb = (unsigned short*)take((size_t)NN * 256 * 2);
  unsigned short* w1b   = (unsigned short*)take((size_t)HID * INDIM * 2);
  unsigned short* w2b   = (unsigned short*)take((size_t)MSGD * HID * 2);
  unsigned short* wihb  = (unsigned short*)take((size_t)768 * 256 * 2);
  unsigned short* whhb  = (unsigned short*)take((size_t)768 * 256 * 2);

  float* outf = (float*)d_out;

  hipMemsetAsync(sums, 0, (size_t)NN * 256 * 4, stream);
  hipMemsetAsync(counts, 0, (size_t)NN * 4, stream);
  hipMemsetAsync(flags, 0, (size_t)NN * 4, stream);

  int n1 = HID * INDIM;
  int n2 = MSGD * HID;
  int n3 = 768 * 256;
  cvt_bf16<<<(n1 + 255) / 256, 256, 0, stream>>>(w1, w1b, n1);
  cvt_bf16<<<(n2 + 255) / 256, 256, 0, stream>>>(w2, w2b, n2);
  cvt_bf16<<<(n3 + 255) / 256, 256, 0, stream>>>(wih, wihb, n3);
  cvt_bf16<<<(n3 + 255) / 256, 256, 0, stream>>>(whh, whhb, n3);

  mark_k<<<E_EDGES / 256, 256, 0, stream>>>(dst, flags, counts);

  // h = relu(X @ w1^T + b1) with X built on the fly
  gemm1_fused<<<dim3((E_EDGES / 128) * (HID / 256)), 512, 0, stream>>>(
      src, dmem, edge, rel, tw, tb, (const bf16_t*)w1b, b1, hb);

  // msg = h @ w2^T + b2, scattered directly: sums[dst[e]] += msg[e]
  gemm_bt2<0, 2, 0><<<dim3(1, E_EDGES / 128), 512, 0, stream>>>(
      (const bf16_t*)hb, (const bf16_t*)w2b, b2, nullptr,
      nullptr, nullptr, nullptr, dst, sums, E_EDGES, MSGD, HID);

  fill_k<<<NN / 256, 256, 0, stream>>>(outf, slot_id);
  scan_k<<<1, 1024, 0, stream>>>(flags, rank);
  scatter_ids<<<NN / 256, 256, 0, stream>>>(flags, rank, outf, slot_id);
  agg_pack<<<NN, 256, 0, stream>>>(slot_id, sums, counts, dmem, aggb, prevb);

  // gi = agg @ w_ih^T + b_ih ; gh = prev @ w_hh^T + b_hh  (bf16 out)
  gemm_bt2<0, 1, 1><<<dim3(768 / 256, NN / 128, 2), 512, 0, stream>>>(
      (const bf16_t*)aggb, (const bf16_t*)wihb, bih, gib,
      (const bf16_t*)prevb, bhh, ghb, nullptr, nullptr, NN, 768, 256);

  gru_gate<<<NN, 256, 0, stream>>>(gib, ghb, dmem, outf);
}